// Round 3
// baseline (209.664 us; speedup 1.0000x reference)
//
#include <hip/hip_runtime.h>

#define B_ 4
#define N_ 384
#define D_ 64
#define H_ 64
#define BN_ (B_ * N_)   // 1536
#define ROW_ (N_ * H_)  // 24576 floats per batch of PA/PC

// ---------------------------------------------------------------------------
// Kernel A: projections.
//   PAxx[b,j,h] = sum_d X[b,j,d] * Wxx1[d,h]
//   PCxx[b,i,h] = sum_d X[b,i,d] * Wxx1[64+d,h] + bxx1[h]
//   PAyx[b,j,h] = sum_d Y[b,j,d] * Wyx1[d,h]
//   PCyx[b,i,h] = sum_d X[b,i,d] * Wyx1[64+d,h] + byx1[h]
// grid = B*N blocks (one (b,n) row), 256 threads = 4 arrays x 64 h.
// ---------------------------------------------------------------------------
__global__ __launch_bounds__(256) void proj_kernel(
    const float* __restrict__ X, const float* __restrict__ Y,
    const float* __restrict__ Wxx1, const float* __restrict__ bxx1,
    const float* __restrict__ Wyx1, const float* __restrict__ byx1,
    float* __restrict__ PAxx, float* __restrict__ PCxx,
    float* __restrict__ PAyx, float* __restrict__ PCyx)
{
    int blk = blockIdx.x;            // b*N + n
    int t = threadIdx.x;
    int which = t >> 6, h = t & 63;

    __shared__ float xrow[64];
    __shared__ float yrow[64];
    if (t < 64) xrow[t] = X[blk * 64 + t];
    else if (t < 128) yrow[t - 64] = Y[blk * 64 + (t - 64)];
    __syncthreads();

    const float* v = (which == 2) ? yrow : xrow;
    const float* W = (which < 2) ? Wxx1 : Wyx1;
    int rowoff = (which & 1) ? 64 : 0;

    float acc = 0.f;
    if (which == 1) acc = bxx1[h];
    if (which == 3) acc = byx1[h];
#pragma unroll
    for (int d = 0; d < 64; ++d)
        acc = fmaf(v[d], W[(rowoff + d) * 64 + h], acc);

    float* dst = (which == 0) ? PAxx : (which == 1) ? PCxx
               : (which == 2) ? PAyx : PCyx;
    dst[blk * 64 + h] = acc;
}

// ---------------------------------------------------------------------------
// Kernel B: per (b,i), for branches {xx, yx}:
//   Z[k] = max_j ( relu(PA[b,j,:] + PC[b,i,:]) . W2[:,k] )
// then diff[b,i,k] = (Zxx[k]+b2xx[k]) - (Zyx[k]+b2yx[k]).
// 256 threads: lane k = t&63 owns output column k; wave w = t>>6 owns a
// quarter of the j range. W2 column cached in 64 VGPRs per lane.
// ---------------------------------------------------------------------------
__global__ __launch_bounds__(256) void pair_kernel(
    const float* __restrict__ PAxx, const float* __restrict__ PCxx,
    const float* __restrict__ PAyx, const float* __restrict__ PCyx,
    const float* __restrict__ W2xx, const float* __restrict__ b2xx,
    const float* __restrict__ W2yx, const float* __restrict__ b2yx,
    float* __restrict__ diff)
{
    int blk = blockIdx.x;            // b*N + i
    int b = blk / N_;
    int t = threadIdx.x;
    int w = t >> 6, k = t & 63;

    __shared__ float pc[64];
    __shared__ float rbuf[16][64];   // relu tile: 16 j rows x 64 h
    __shared__ float mbuf[4][64];
    __shared__ float zb[2][64];

    for (int br = 0; br < 2; ++br) {
        const float* PA = br ? PAyx : PAxx;
        const float* PC = br ? PCyx : PCxx;
        const float* W2 = br ? W2yx : W2xx;

        if (t < 64) pc[t] = PC[blk * 64 + t];
        __syncthreads();

        // W2 column k into registers (reused for all 384 j)
        float w2c[64];
#pragma unroll
        for (int h = 0; h < 64; ++h) w2c[h] = W2[h * 64 + k];

        float m = -1e30f;
        const float* PArow = PA + b * ROW_;

        for (int t0 = 0; t0 < N_; t0 += 16) {
            // cooperative relu tile: thread (w,k) fills rows w+4q, column k
#pragma unroll
            for (int q = 0; q < 4; ++q) {
                int jj = w + q * 4;
                rbuf[jj][k] = fmaxf(0.f, PArow[(t0 + jj) * 64 + k] + pc[k]);
            }
            __syncthreads();

            // wave w computes j rows w*4 .. w*4+3 (4 independent FMA chains)
            float a0 = 0.f, a1 = 0.f, a2 = 0.f, a3 = 0.f;
#pragma unroll
            for (int h4 = 0; h4 < 16; ++h4) {
                float4 r0 = *(const float4*)&rbuf[w * 4 + 0][h4 * 4];
                float4 r1 = *(const float4*)&rbuf[w * 4 + 1][h4 * 4];
                float4 r2 = *(const float4*)&rbuf[w * 4 + 2][h4 * 4];
                float4 r3 = *(const float4*)&rbuf[w * 4 + 3][h4 * 4];
                float c0 = w2c[h4 * 4 + 0], c1 = w2c[h4 * 4 + 1];
                float c2 = w2c[h4 * 4 + 2], c3 = w2c[h4 * 4 + 3];
                a0 = fmaf(r0.x, c0, a0); a0 = fmaf(r0.y, c1, a0);
                a0 = fmaf(r0.z, c2, a0); a0 = fmaf(r0.w, c3, a0);
                a1 = fmaf(r1.x, c0, a1); a1 = fmaf(r1.y, c1, a1);
                a1 = fmaf(r1.z, c2, a1); a1 = fmaf(r1.w, c3, a1);
                a2 = fmaf(r2.x, c0, a2); a2 = fmaf(r2.y, c1, a2);
                a2 = fmaf(r2.z, c2, a2); a2 = fmaf(r2.w, c3, a2);
                a3 = fmaf(r3.x, c0, a3); a3 = fmaf(r3.y, c1, a3);
                a3 = fmaf(r3.z, c2, a3); a3 = fmaf(r3.w, c3, a3);
            }
            m = fmaxf(m, fmaxf(fmaxf(a0, a1), fmaxf(a2, a3)));
            __syncthreads();
        }

        mbuf[w][k] = m;
        __syncthreads();
        if (t < 64)
            zb[br][t] = fmaxf(fmaxf(mbuf[0][t], mbuf[1][t]),
                              fmaxf(mbuf[2][t], mbuf[3][t]));
        __syncthreads();
    }

    if (t < 64) {
        float d = (zb[0][t] + b2xx[t]) - (zb[1][t] + b2yx[t]);
        diff[blk * 64 + t] = d;
    }
}

// ---------------------------------------------------------------------------
// Kernel C: Z_X[b,h] = sum_i diff[b,i,h]; decoder.
// z = [Z_X, Z_X] so z@Wd1 = Z_X @ (Wd1[:64] + Wd1[64:]).
// ---------------------------------------------------------------------------
__global__ __launch_bounds__(256) void head_kernel(
    const float* __restrict__ diff, const float* __restrict__ Wd1,
    const float* __restrict__ bd1, const float* __restrict__ Wd2,
    const float* __restrict__ bd2, float* __restrict__ out)
{
    int b = blockIdx.x;
    int t = threadIdx.x;
    int ig = t >> 6, h = t & 63;

    __shared__ float sbuf[4][64];
    __shared__ float zx[64];

    float s = 0.f;
    for (int i = ig; i < N_; i += 4) s += diff[(b * N_ + i) * 64 + h];
    sbuf[ig][h] = s;
    __syncthreads();
    if (t < 64) zx[t] = sbuf[0][t] + sbuf[1][t] + sbuf[2][t] + sbuf[3][t];
    __syncthreads();

    if (t < 64) {
        float acc = bd1[t];
#pragma unroll
        for (int d = 0; d < 64; ++d)
            acc = fmaf(zx[d], Wd1[d * 64 + t] + Wd1[(64 + d) * 64 + t], acc);
        float h1 = fmaxf(acc, 0.f);
        float r = h1 * Wd2[t];
#pragma unroll
        for (int off = 32; off; off >>= 1) r += __shfl_down(r, off);
        if (t == 0) out[b] = r + bd2[0];
    }
}

extern "C" void kernel_launch(void* const* d_in, const int* in_sizes, int n_in,
                              void* d_out, int out_size, void* d_ws, size_t ws_size,
                              hipStream_t stream) {
    const float* X    = (const float*)d_in[0];
    const float* Y    = (const float*)d_in[1];
    const float* Wxx1 = (const float*)d_in[2];
    const float* bxx1 = (const float*)d_in[3];
    const float* W2xx = (const float*)d_in[4];
    const float* b2xx = (const float*)d_in[5];
    // d_in[6..9]  = xy branch (dead code)
    const float* Wyx1 = (const float*)d_in[10];
    const float* byx1 = (const float*)d_in[11];
    const float* W2yx = (const float*)d_in[12];
    const float* b2yx = (const float*)d_in[13];
    // d_in[14..17] = yy branch (dead code)
    const float* Wd1  = (const float*)d_in[18];
    const float* bd1  = (const float*)d_in[19];
    const float* Wd2  = (const float*)d_in[20];
    const float* bd2  = (const float*)d_in[21];

    float* ws   = (float*)d_ws;
    float* PAxx = ws;
    float* PCxx = ws + 1 * (BN_ * H_);
    float* PAyx = ws + 2 * (BN_ * H_);
    float* PCyx = ws + 3 * (BN_ * H_);
    float* diff = ws + 4 * (BN_ * H_);

    proj_kernel<<<BN_, 256, 0, stream>>>(X, Y, Wxx1, bxx1, Wyx1, byx1,
                                         PAxx, PCxx, PAyx, PCyx);
    pair_kernel<<<BN_, 256, 0, stream>>>(PAxx, PCxx, PAyx, PCyx,
                                         W2xx, b2xx, W2yx, b2yx, diff);
    head_kernel<<<B_, 256, 0, stream>>>(diff, Wd1, bd1, Wd2, bd2, (float*)d_out);
}

// Round 4
// 82.491 us; speedup vs baseline: 2.5417x; 2.5417x over previous
//
#include <hip/hip_runtime.h>

#define B_ 4
#define N_ 384
#define D_ 64
#define H_ 64
#define BN_ (B_ * N_)   // 1536
#define ROW_ (N_ * H_)  // 24576 floats per batch of PA/PC

typedef float f32x4 __attribute__((ext_vector_type(4)));
typedef _Float16 half8 __attribute__((ext_vector_type(8)));

// ---------------------------------------------------------------------------
// Kernel A: projections (unchanged from verified baseline).
// ---------------------------------------------------------------------------
__global__ __launch_bounds__(256) void proj_kernel(
    const float* __restrict__ X, const float* __restrict__ Y,
    const float* __restrict__ Wxx1, const float* __restrict__ bxx1,
    const float* __restrict__ Wyx1, const float* __restrict__ byx1,
    float* __restrict__ PAxx, float* __restrict__ PCxx,
    float* __restrict__ PAyx, float* __restrict__ PCyx)
{
    int blk = blockIdx.x;            // b*N + n
    int t = threadIdx.x;
    int which = t >> 6, h = t & 63;

    __shared__ float xrow[64];
    __shared__ float yrow[64];
    if (t < 64) xrow[t] = X[blk * 64 + t];
    else if (t < 128) yrow[t - 64] = Y[blk * 64 + (t - 64)];
    __syncthreads();

    const float* v = (which == 2) ? yrow : xrow;
    const float* W = (which < 2) ? Wxx1 : Wyx1;
    int rowoff = (which & 1) ? 64 : 0;

    float acc = 0.f;
    if (which == 1) acc = bxx1[h];
    if (which == 3) acc = byx1[h];
#pragma unroll
    for (int d = 0; d < 64; ++d)
        acc = fmaf(v[d], W[(rowoff + d) * 64 + h], acc);

    float* dst = (which == 0) ? PAxx : (which == 1) ? PCxx
               : (which == 2) ? PAyx : PCyx;
    dst[blk * 64 + h] = acc;
}

// ---------------------------------------------------------------------------
// Kernel A2: pre-split W2 (both branches) into f16 hi/lo MFMA B-fragments.
// Fragment layout: [br][q=nt*4+kt*2+part][lane=64][e=8] f16, so the pair
// kernel loads one half8 (16B) per lane, coalesced.
//   B element for lane l, elem e: h = kt*32 + (l>>4)*8 + e, n = nt*16 + (l&15)
// ---------------------------------------------------------------------------
__global__ __launch_bounds__(256) void w2prep_kernel(
    const float* __restrict__ W2xx, const float* __restrict__ W2yx,
    _Float16* __restrict__ out)
{
    int t = threadIdx.x + blockIdx.x * blockDim.x;   // 2048 frag-lanes
    if (t >= 2048) return;
    int br = t >> 10;
    int q  = (t >> 6) & 15;
    int l  = t & 63;
    int nt = q >> 2, kt = (q >> 1) & 1, part = q & 1;
    const float* W2 = br ? W2yx : W2xx;
    int n = nt * 16 + (l & 15);
    int g = l >> 4;
    _Float16* dst = out + t * 8;
#pragma unroll
    for (int e = 0; e < 8; ++e) {
        int h = kt * 32 + g * 8 + e;
        float v = W2[h * 64 + n];
        _Float16 hi = (_Float16)v;
        _Float16 lo = (_Float16)(v - (float)hi);
        dst[e] = part ? lo : hi;
    }
}

// ---------------------------------------------------------------------------
// Kernel B: per (b,i), for branches {xx, yx}:
//   Z[k] = max_j ( relu(PA[b,j,:] + PC[b,i,:]) . W2[:,k] )
// via split-f16 MFMA (hi*hi + hi*lo + lo*hi). 4 waves; wave w owns j rows
// w*96..w*96+95 and ALL 64 k columns. No barriers in the main loop.
// A fragment: lane l = (g,m): row j = tile+m(=l&15), h = kt*32+g*8+e.
// C layout (verified m89): col k = lane&15, row = (lane>>4)*4+reg; max over
// rows makes any row permutation harmless.
// ---------------------------------------------------------------------------
__global__ __launch_bounds__(256) void pair_mfma_kernel(
    const float* __restrict__ PAxx, const float* __restrict__ PCxx,
    const float* __restrict__ PAyx, const float* __restrict__ PCyx,
    const half8* __restrict__ W2F,
    const float* __restrict__ b2xx, const float* __restrict__ b2yx,
    float* __restrict__ diff)
{
    int blk = blockIdx.x;            // b*N + i
    int b = blk / N_;
    int t = threadIdx.x;
    int w = t >> 6, l = t & 63;
    int g = l >> 4, m = l & 15;

    __shared__ float zsh[2][4][64];  // [br][wave][k]

#pragma unroll
    for (int br = 0; br < 2; ++br) {
        const float* PA = br ? PAyx : PAxx;
        const float* PC = br ? PCyx : PCxx;

        // B fragments: bf[nt][kt][part], 16 x half8 = 64 VGPRs
        half8 bf[4][2][2];
        const half8* Wb = W2F + br * 1024;
#pragma unroll
        for (int q = 0; q < 16; ++q)
            bf[q >> 2][(q >> 1) & 1][q & 1] = Wb[q * 64 + l];

        // pc values this lane needs: h = kt*32 + g*8 + {0..7}
        f32x4 pcq[4];
#pragma unroll
        for (int kt = 0; kt < 2; ++kt) {
            pcq[kt * 2 + 0] = *(const f32x4*)(PC + blk * 64 + kt * 32 + g * 8);
            pcq[kt * 2 + 1] = *(const f32x4*)(PC + blk * 64 + kt * 32 + g * 8 + 4);
        }

        float mm[4];
#pragma unroll
        for (int nt = 0; nt < 4; ++nt) mm[nt] = -3.0e38f;

        const float* pabase = PA + b * ROW_ + (w * 96 + m) * 64 + g * 8;

        for (int mt = 0; mt < 6; ++mt) {
            const float* par = pabase + mt * 16 * 64;
            f32x4 pa[4];
            pa[0] = *(const f32x4*)(par);
            pa[1] = *(const f32x4*)(par + 4);
            pa[2] = *(const f32x4*)(par + 32);
            pa[3] = *(const f32x4*)(par + 36);

            half8 ah[2], al[2];
#pragma unroll
            for (int kt = 0; kt < 2; ++kt)
#pragma unroll
                for (int e = 0; e < 8; ++e) {
                    float x = pa[kt * 2 + (e >> 2)][e & 3]
                            + pcq[kt * 2 + (e >> 2)][e & 3];
                    x = fmaxf(x, 0.f);
                    _Float16 hi = (_Float16)x;
                    float hf = (float)hi;
                    _Float16 lo = (_Float16)(x - hf);
                    ah[kt][e] = hi;
                    al[kt][e] = lo;
                }

#pragma unroll
            for (int nt = 0; nt < 4; ++nt) {
                f32x4 a = {0.f, 0.f, 0.f, 0.f};
#pragma unroll
                for (int kt = 0; kt < 2; ++kt) {
                    a = __builtin_amdgcn_mfma_f32_16x16x32_f16(ah[kt], bf[nt][kt][0], a, 0, 0, 0);
                    a = __builtin_amdgcn_mfma_f32_16x16x32_f16(ah[kt], bf[nt][kt][1], a, 0, 0, 0);
                    a = __builtin_amdgcn_mfma_f32_16x16x32_f16(al[kt], bf[nt][kt][0], a, 0, 0, 0);
                }
                mm[nt] = fmaxf(mm[nt],
                               fmaxf(fmaxf(a[0], a[1]), fmaxf(a[2], a[3])));
            }
        }

        // cross-lane max over the 4 (lane>>4) row groups; col = nt*16 + (l&15)
#pragma unroll
        for (int nt = 0; nt < 4; ++nt) {
            float v = mm[nt];
            v = fmaxf(v, __shfl_xor(v, 16));
            v = fmaxf(v, __shfl_xor(v, 32));
            if (l < 16) zsh[br][w][nt * 16 + l] = v;
        }
    }
    __syncthreads();

    if (t < 64) {
        float zxx = fmaxf(fmaxf(zsh[0][0][t], zsh[0][1][t]),
                          fmaxf(zsh[0][2][t], zsh[0][3][t]));
        float zyx = fmaxf(fmaxf(zsh[1][0][t], zsh[1][1][t]),
                          fmaxf(zsh[1][2][t], zsh[1][3][t]));
        diff[blk * 64 + t] = (zxx + b2xx[t]) - (zyx + b2yx[t]);
    }
}

// ---------------------------------------------------------------------------
// Kernel C: Z_X[b,h] = sum_i diff[b,i,h]; decoder (unchanged).
// ---------------------------------------------------------------------------
__global__ __launch_bounds__(256) void head_kernel(
    const float* __restrict__ diff, const float* __restrict__ Wd1,
    const float* __restrict__ bd1, const float* __restrict__ Wd2,
    const float* __restrict__ bd2, float* __restrict__ out)
{
    int b = blockIdx.x;
    int t = threadIdx.x;
    int ig = t >> 6, h = t & 63;

    __shared__ float sbuf[4][64];
    __shared__ float zx[64];

    float s = 0.f;
    for (int i = ig; i < N_; i += 4) s += diff[(b * N_ + i) * 64 + h];
    sbuf[ig][h] = s;
    __syncthreads();
    if (t < 64) zx[t] = sbuf[0][t] + sbuf[1][t] + sbuf[2][t] + sbuf[3][t];
    __syncthreads();

    if (t < 64) {
        float acc = bd1[t];
#pragma unroll
        for (int d = 0; d < 64; ++d)
            acc = fmaf(zx[d], Wd1[d * 64 + t] + Wd1[(64 + d) * 64 + t], acc);
        float h1 = fmaxf(acc, 0.f);
        float r = h1 * Wd2[t];
#pragma unroll
        for (int off = 32; off; off >>= 1) r += __shfl_down(r, off);
        if (t == 0) out[b] = r + bd2[0];
    }
}

extern "C" void kernel_launch(void* const* d_in, const int* in_sizes, int n_in,
                              void* d_out, int out_size, void* d_ws, size_t ws_size,
                              hipStream_t stream) {
    const float* X    = (const float*)d_in[0];
    const float* Y    = (const float*)d_in[1];
    const float* Wxx1 = (const float*)d_in[2];
    const float* bxx1 = (const float*)d_in[3];
    const float* W2xx = (const float*)d_in[4];
    const float* b2xx = (const float*)d_in[5];
    // d_in[6..9]  = xy branch (dead code)
    const float* Wyx1 = (const float*)d_in[10];
    const float* byx1 = (const float*)d_in[11];
    const float* W2yx = (const float*)d_in[12];
    const float* b2yx = (const float*)d_in[13];
    // d_in[14..17] = yy branch (dead code)
    const float* Wd1  = (const float*)d_in[18];
    const float* bd1  = (const float*)d_in[19];
    const float* Wd2  = (const float*)d_in[20];
    const float* bd2  = (const float*)d_in[21];

    float* ws   = (float*)d_ws;
    float* PAxx = ws;
    float* PCxx = ws + 1 * (BN_ * H_);
    float* PAyx = ws + 2 * (BN_ * H_);
    float* PCyx = ws + 3 * (BN_ * H_);
    float* diff = ws + 4 * (BN_ * H_);
    _Float16* W2F = (_Float16*)(ws + 5 * (BN_ * H_));  // 32 KiB, 16B-aligned

    proj_kernel<<<BN_, 256, 0, stream>>>(X, Y, Wxx1, bxx1, Wyx1, byx1,
                                         PAxx, PCxx, PAyx, PCyx);
    w2prep_kernel<<<8, 256, 0, stream>>>(W2xx, W2yx, W2F);
    pair_mfma_kernel<<<BN_, 256, 0, stream>>>(PAxx, PCxx, PAyx, PCyx,
                                              (const half8*)W2F,
                                              b2xx, b2yx, diff);
    head_kernel<<<B_, 256, 0, stream>>>(diff, Wd1, bd1, Wd2, bd2, (float*)d_out);
}